// Round 5
// baseline (366.207 us; speedup 1.0000x reference)
//
#include <hip/hip_runtime.h>
#include <hip/hip_bf16.h>
#include <hip/hip_fp16.h>

// GraphSAGE 3-layer + pool + linear.
// R20: R19 (288.8us) + feature-sliced agg. agg was ~36us/layer (108us
// total): 153.6MB of random 256B gathers from a 12.8MB table that does NOT
// fit a 4MB per-XCD L2 (~31% hit, rest LLC => 4.7TB/s effective). Slice the
// feature dim 4x32 cols (64B = one line per row-slice); blk = chunk*4 + s so
// under round-robin blk%8 XCD mapping each XCD serves ONE slice (3.2MB,
// L2-resident). esrc read nontemporally (4x re-read, don't evict the slice).
// Same line count, same summation order -> bit-identical agg16.
// mega_prep / gemm / pool unchanged from R19.

#define FH 128
#define OUTD 256
#define SLOTS 64
#define PWB 96   // weight-prep blocks: 48 pairs x 8 ot = 384 waves

typedef unsigned int u32;
typedef unsigned short u16;
typedef __attribute__((ext_vector_type(8))) _Float16 f16frag;
typedef __attribute__((ext_vector_type(4))) float f4frag;

typedef __attribute__((address_space(3))) u32 lds_u32;
typedef __attribute__((address_space(1))) const u32 glb_u32;

__device__ inline void async_copy16(const void* g, void* l) {
    __builtin_amdgcn_global_load_lds((glb_u32*)g, (lds_u32*)l, 16, 0, 0);
}

// ====== mega prep: prep_w | scatter | graph bounds | prep_x (in block order)
__global__ void mega_prep(const float* __restrict__ x, u16* __restrict__ x16, int n4,
                          const float* __restrict__ W0, const float* __restrict__ W1,
                          const float* __restrict__ W2, const float* __restrict__ W3,
                          const float* __restrict__ W4, const float* __restrict__ W5,
                          uint4* __restrict__ Bf,
                          const int* __restrict__ src, const int* __restrict__ dst,
                          int* __restrict__ cursor, int* __restrict__ esrc, int E, int SC,
                          const int* __restrict__ batch, int* __restrict__ gstart,
                          int n, int g, int GBND) {
    int blk = blockIdx.x;
    if (blk < PWB) {
        // one wave per (pair, ot): pair = wid>>3, ot = wid&7
        int wid = blk * 4 + (threadIdx.x >> 6);      // 0..383
        int pair = wid >> 3;                         // 0..47
        int ot = wid & 7;
        int ks = pair & 7;
        int arr = pair >> 3;
        int l = threadIdx.x & 63;
        const float* Ws[6] = {W0, W1, W2, W3, W4, W5};
        const float* W = Ws[arr];
        bool use_lo = (ks >= 4);
        int kb = (ks & 3) * 32 + (l >> 4) * 8;
        int o = ot * 16 + (l & 15);
        float4 v0 = *(const float4*)(W + o * 128 + kb);
        float4 v1 = *(const float4*)(W + o * 128 + kb + 4);
        float vv[8] = {v0.x, v0.y, v0.z, v0.w, v1.x, v1.y, v1.z, v1.w};
        u32 h[8];
        #pragma unroll
        for (int i = 0; i < 8; ++i) {
            float v = vv[i];
            __half hi = __float2half(v);
            if (use_lo) {
                float rem = v - __half2float(hi);
                __half lo = __float2half(rem);
                h[i] = *(u16*)&lo;
            } else {
                h[i] = *(u16*)&hi;
            }
        }
        uint4 u;
        u.x = h[0] | (h[1] << 16);
        u.y = h[2] | (h[3] << 16);
        u.z = h[4] | (h[5] << 16);
        u.w = h[6] | (h[7] << 16);
        Bf[(size_t)arr * 4096 + (ks * 8 + ot) * 64 + l] = u;
    } else if (blk < PWB + SC) {
        int e = (blk - PWB) * 256 + threadIdx.x;
        if (e < E) {
            int d = dst[e];
            int pos = atomicAdd(&cursor[d], 1);
            if (pos < SLOTS) esrc[(size_t)d * SLOTS + pos] = src[e];
        }
    } else if (blk < PWB + SC + GBND) {
        int i = (blk - PWB - SC) * 256 + threadIdx.x;
        if (i >= n) return;
        int b = batch[i];
        int pb = (i == 0) ? -1 : batch[i - 1];
        for (int q = pb + 1; q <= b; ++q) gstart[q] = i;
        if (i == n - 1) {
            for (int q = b + 1; q <= g; ++q) gstart[q] = n;
        }
    } else {
        int id = (blk - PWB - SC - GBND) * 256 + threadIdx.x;
        if (id >= n4) return;
        float4 v = *(const float4*)(x + (size_t)id * 4);
        __half h0 = __float2half(v.x), h1 = __float2half(v.y);
        __half h2 = __float2half(v.z), h3 = __float2half(v.w);
        ushort4 s;
        s.x = *(u16*)&h0; s.y = *(u16*)&h1; s.z = *(u16*)&h2; s.w = *(u16*)&h3;
        *(ushort4*)(x16 + (size_t)id * 4) = s;
    }
}

// --------------------------------------------------- mean aggregation
// Feature-sliced: blk = chunk*4 + s; 16 nodes/block, 16 lanes/node, slice s
// covers feature cols [s*32, s*32+32) = 64B (one cache line) per row.
// Round-robin blk%8 XCD mapping => XCD x serves only slice x%4 => per-XCD
// gather working set 3.2MB (L2-resident). Summation order identical to R19
// (a0..a3 edge mapping, ((a0+a1)+a2)+a3 reduce) => bit-identical output.
__device__ inline void add2(float2& a, u32 w) {
    float2 f = __half22float2(*(__half2*)&w);
    a.x += f.x; a.y += f.y;
}

__global__ void agg_kernel(const u16* __restrict__ h16,
                           const int* __restrict__ deg, const int* __restrict__ esrc,
                           u16* __restrict__ agg16, int n_nodes) {
    int s = blockIdx.x & 3;
    int chunk = blockIdx.x >> 2;
    int node = chunk * 16 + (threadIdx.x >> 4);
    if (node >= n_nodes) return;
    int lane = threadIdx.x & 15;
    int fo = s * 32 + lane * 2;                 // u16 index within row
    const u16* hp = h16 + fo;
    int d = deg[node];
    int s0 = node * SLOTS, s1 = s0 + min(d, SLOTS);
    float2 a0 = {0.f, 0.f}, a1 = {0.f, 0.f}, a2 = {0.f, 0.f}, a3 = {0.f, 0.f};
    int j = s0;
    for (; j + 8 <= s1; j += 8) {
        int i0 = __builtin_nontemporal_load(esrc + j);
        int i1 = __builtin_nontemporal_load(esrc + j + 1);
        int i2 = __builtin_nontemporal_load(esrc + j + 2);
        int i3 = __builtin_nontemporal_load(esrc + j + 3);
        int i4 = __builtin_nontemporal_load(esrc + j + 4);
        int i5 = __builtin_nontemporal_load(esrc + j + 5);
        int i6 = __builtin_nontemporal_load(esrc + j + 6);
        int i7 = __builtin_nontemporal_load(esrc + j + 7);
        u32 w0 = *(const u32*)(hp + (size_t)i0 * FH);
        u32 w1 = *(const u32*)(hp + (size_t)i1 * FH);
        u32 w2 = *(const u32*)(hp + (size_t)i2 * FH);
        u32 w3 = *(const u32*)(hp + (size_t)i3 * FH);
        u32 w4 = *(const u32*)(hp + (size_t)i4 * FH);
        u32 w5 = *(const u32*)(hp + (size_t)i5 * FH);
        u32 w6 = *(const u32*)(hp + (size_t)i6 * FH);
        u32 w7 = *(const u32*)(hp + (size_t)i7 * FH);
        add2(a0, w0); add2(a1, w1); add2(a2, w2); add2(a3, w3);
        add2(a0, w4); add2(a1, w5); add2(a2, w6); add2(a3, w7);
    }
    if (j + 4 <= s1) {
        int i0 = __builtin_nontemporal_load(esrc + j);
        int i1 = __builtin_nontemporal_load(esrc + j + 1);
        int i2 = __builtin_nontemporal_load(esrc + j + 2);
        int i3 = __builtin_nontemporal_load(esrc + j + 3);
        u32 w0 = *(const u32*)(hp + (size_t)i0 * FH);
        u32 w1 = *(const u32*)(hp + (size_t)i1 * FH);
        u32 w2 = *(const u32*)(hp + (size_t)i2 * FH);
        u32 w3 = *(const u32*)(hp + (size_t)i3 * FH);
        add2(a0, w0); add2(a1, w1); add2(a2, w2); add2(a3, w3);
        j += 4;
    }
    for (; j < s1; ++j) {
        int i0 = __builtin_nontemporal_load(esrc + j);
        u32 w0 = *(const u32*)(hp + (size_t)i0 * FH);
        add2(a0, w0);
    }
    float di = 1.0f / (float)max(d, 1);
    float fx = (a0.x + a1.x + a2.x + a3.x) * di;
    float fy = (a0.y + a1.y + a2.y + a3.y) * di;
    __half hx = __float2half(fx), hy = __float2half(fy);
    u32 oh = (u32)(*(u16*)&hx) | ((u32)(*(u16*)&hy) << 16);
    *(u32*)(agg16 + (size_t)node * FH + fo) = oh;
}

// ----------------------------------------------------------- MFMA SAGE GEMM
// Exact R11/R15 structure (proven best): 256 thr / 4 waves, 192-node tile,
// per-source async global_load_lds B staging (64 KB), A prefetch in regs,
// pure-LDS K-loop (hi then lo phase).
__global__ __launch_bounds__(256, 2)
void mfma_gemm(const u16* __restrict__ A1, const u16* __restrict__ A2,
               const uint4* __restrict__ Bf1, const uint4* __restrict__ Bf2,
               const float* __restrict__ bias, u16* __restrict__ out16,
               int do_relu) {
    __shared__ uint4 Bl[4096];  // 64 KB
    int tid = threadIdx.x;
    int l = tid & 63;
    int wv = tid >> 6;
    int bn0 = blockIdx.x * 192 + wv * 48;
    int m = l & 15, q = l >> 4;

    f4frag acc[3][8];
    #pragma unroll
    for (int i = 0; i < 3; ++i)
        #pragma unroll
        for (int o = 0; o < 8; ++o)
            acc[i][o] = (f4frag){0.f, 0.f, 0.f, 0.f};

    #pragma unroll
    for (int p = 0; p < 2; ++p) {
        const u16* P = p ? A2 : A1;
        const uint4* Bf = p ? Bf2 : Bf1;

        // A prefetch (registers; in flight across the barrier)
        f16frag Af[3][4];
        #pragma unroll
        for (int nt = 0; nt < 3; ++nt)
            #pragma unroll
            for (int s = 0; s < 4; ++s)
                Af[nt][s] = *(const f16frag*)(P + (size_t)(bn0 + nt * 16 + m) * FH + s * 32 + q * 8);

        __syncthreads();   // all waves done with previous source's Bl

        #pragma unroll
        for (int u = 0; u < 16; ++u)
            async_copy16(Bf + (size_t)u * 256 + wv * 64 + l,
                         &Bl[u * 256 + wv * 64]);
        __syncthreads();   // drains vmcnt -> staging complete

        #pragma unroll
        for (int s = 0; s < 4; ++s) {
            {
                f16frag B[8];
                #pragma unroll
                for (int ot = 0; ot < 8; ++ot)
                    B[ot] = *(const f16frag*)&Bl[(size_t)(s * 8 + ot) * 64 + l];
                #pragma unroll
                for (int ot = 0; ot < 8; ++ot)
                    #pragma unroll
                    for (int nt = 0; nt < 3; ++nt)
                        acc[nt][ot] = __builtin_amdgcn_mfma_f32_16x16x32_f16(Af[nt][s], B[ot], acc[nt][ot], 0, 0, 0);
            }
            {
                f16frag B[8];
                #pragma unroll
                for (int ot = 0; ot < 8; ++ot)
                    B[ot] = *(const f16frag*)&Bl[(size_t)((s + 4) * 8 + ot) * 64 + l];
                #pragma unroll
                for (int ot = 0; ot < 8; ++ot)
                    #pragma unroll
                    for (int nt = 0; nt < 3; ++nt)
                        acc[nt][ot] = __builtin_amdgcn_mfma_f32_16x16x32_f16(Af[nt][s], B[ot], acc[nt][ot], 0, 0, 0);
            }
        }
    }

    #pragma unroll
    for (int nt = 0; nt < 3; ++nt)
        #pragma unroll
        for (int r = 0; r < 4; ++r) {
            int node = bn0 + nt * 16 + q * 4 + r;
            #pragma unroll
            for (int ot = 0; ot < 8; ++ot) {
                float v = acc[nt][ot][r] + bias[ot * 16 + m];
                if (do_relu) v = fmaxf(v, 0.f);
                __half hv = __float2half(v);
                out16[(size_t)node * FH + ot * 16 + m] = *(u16*)&hv;
            }
        }
}

// --------------------------------------------- fused pooling + final linear
__global__ __launch_bounds__(256, 2)
void pool_final(const u16* __restrict__ h16, const int* __restrict__ gstart,
                const float* __restrict__ Wlin, const float* __restrict__ blin,
                float* __restrict__ out) {
    __shared__ float smax[16][FH];
    __shared__ float ssum[16][FH];
    __shared__ float pr[2 * FH];
    int g = blockIdx.x;
    int tid = threadIdx.x;
    int way = tid >> 4;
    int lane = tid & 15;
    int f = lane * 8;
    int s = gstart[g], e = gstart[g + 1];

    float mx[8], sm[8];
    #pragma unroll
    for (int i = 0; i < 8; ++i) { mx[i] = -INFINITY; sm[i] = 0.f; }
    for (int n = s + way; n < e; n += 16) {
        uint4 u = *(const uint4*)(h16 + (size_t)n * FH + f);
        float2 f0 = __half22float2(*(__half2*)&u.x);
        float2 f1 = __half22float2(*(__half2*)&u.y);
        float2 f2 = __half22float2(*(__half2*)&u.z);
        float2 f3 = __half22float2(*(__half2*)&u.w);
        float v[8] = {f0.x, f0.y, f1.x, f1.y, f2.x, f2.y, f3.x, f3.y};
        #pragma unroll
        for (int i = 0; i < 8; ++i) {
            mx[i] = fmaxf(mx[i], v[i]);
            sm[i] += v[i];
        }
    }
    #pragma unroll
    for (int i = 0; i < 8; ++i) {
        smax[way][f + i] = mx[i];
        ssum[way][f + i] = sm[i];
    }
    __syncthreads();
    int c = e - s;
    if (tid < FH) {
        float m2 = -INFINITY, s2 = 0.f;
        #pragma unroll
        for (int w2 = 0; w2 < 16; ++w2) {
            m2 = fmaxf(m2, smax[w2][tid]);
            s2 += ssum[w2][tid];
        }
        pr[tid] = (c > 0) ? m2 : 0.f;
        pr[FH + tid] = s2 / (float)max(c, 1);
    }
    __syncthreads();
    int o = tid;
    const float4* wr = (const float4*)(Wlin + (size_t)o * (2 * FH));
    float acc = 0.f;
    #pragma unroll
    for (int j = 0; j < (2 * FH) / 4; ++j) {
        float4 wv = wr[j];
        acc += wv.x * pr[j * 4 + 0] + wv.y * pr[j * 4 + 1] +
               wv.z * pr[j * 4 + 2] + wv.w * pr[j * 4 + 3];
    }
    out[(size_t)g * OUTD + o] = acc + blin[o];
}

extern "C" void kernel_launch(void* const* d_in, const int* in_sizes, int n_in,
                              void* d_out, int out_size, void* d_ws, size_t ws_size,
                              hipStream_t stream) {
    const float* x     = (const float*)d_in[0];
    const int*   ei    = (const int*)d_in[1];
    const int*   batch = (const int*)d_in[2];
    const float* W1l = (const float*)d_in[3];
    const float* b1  = (const float*)d_in[4];
    const float* W1r = (const float*)d_in[5];
    const float* W2l = (const float*)d_in[6];
    const float* b2  = (const float*)d_in[7];
    const float* W2r = (const float*)d_in[8];
    const float* W3l = (const float*)d_in[9];
    const float* b3  = (const float*)d_in[10];
    const float* W3r = (const float*)d_in[11];
    const float* Wlin = (const float*)d_in[12];
    const float* blin = (const float*)d_in[13];
    float* out = (float*)d_out;

    const int E = in_sizes[1] / 2;
    const int N = in_sizes[2];
    const int G = out_size / OUTD;
    const int* src = ei;
    const int* dst = ei + E;
    const int GB = (N + 191) / 192;
    const int NP = GB * 192;

    // ---- workspace carve-up ----
    char* w = (char*)d_ws;
    auto alloc = [&](size_t bytes) {
        void* p = (void*)w;
        w += (bytes + 255) & ~(size_t)255;
        return p;
    };
    int*   cursor = (int*)alloc((size_t)N * sizeof(int));          // deg after scatter
    int*   esrc   = (int*)alloc((size_t)N * SLOTS * sizeof(int));  // bucketed edge list
    int*   gstart = (int*)alloc((size_t)(G + 1) * sizeof(int));
    u16*   x16    = (u16*)alloc((size_t)NP * FH * sizeof(u16));
    u16*   agg16  = (u16*)alloc((size_t)NP * FH * sizeof(u16));
    u16*   hA16   = (u16*)alloc((size_t)NP * FH * sizeof(u16));
    u16*   hB16   = (u16*)alloc((size_t)NP * FH * sizeof(u16));
    uint4* BF     = (uint4*)alloc((size_t)6 * 4096 * sizeof(uint4));
    (void)ws_size;

    // ---- single prep dispatch: prep_w | scatter | bounds | prep_x ----
    hipMemsetAsync(cursor, 0, (size_t)N * sizeof(int), stream);
    const int n4 = N * 32;
    const int PX = (n4 + 255) / 256;
    const int SC = (E + 255) / 256;
    const int GBND = (N + 255) / 256;
    mega_prep<<<PWB + SC + GBND + PX, 256, 0, stream>>>(
        x, x16, n4,
        W1l, W1r, W2l, W2r, W3l, W3r, BF,
        src, dst, cursor, esrc, E, SC,
        batch, gstart, N, G, GBND);

    const int agg_grid = ((N + 15) / 16) * 4;   // 4 feature slices per chunk

    // ---- layer 1 ----
    agg_kernel<<<agg_grid, 256, 0, stream>>>(x16, cursor, esrc, agg16, N);
    mfma_gemm<<<GB, 256, 0, stream>>>(agg16, x16, BF + 0 * 4096, BF + 1 * 4096, b1, hA16, 1);
    // ---- layer 2 ----
    agg_kernel<<<agg_grid, 256, 0, stream>>>(hA16, cursor, esrc, agg16, N);
    mfma_gemm<<<GB, 256, 0, stream>>>(agg16, hA16, BF + 2 * 4096, BF + 3 * 4096, b2, hB16, 1);
    // ---- layer 3 ----
    agg_kernel<<<agg_grid, 256, 0, stream>>>(hB16, cursor, esrc, agg16, N);
    mfma_gemm<<<GB, 256, 0, stream>>>(agg16, hB16, BF + 4 * 4096, BF + 5 * 4096, b3, hA16, 0);

    // ---- fused pool + head ----
    pool_final<<<G, 256, 0, stream>>>(hA16, gstart, Wlin, blin, out);
}

// Round 6
// 284.992 us; speedup vs baseline: 1.2850x; 1.2850x over previous
//
#include <hip/hip_runtime.h>
#include <hip/hip_bf16.h>
#include <hip/hip_fp16.h>

// GraphSAGE 3-layer + pool + linear.
// R21: revert R20's feature-sliced agg (103MB still missed L2; 4B loads
// killed MLP -> 56us/layer). Back to R19's uint4 agg (proven 36us/layer,
// ~75% of random-64B fabric ceiling) with int4 bucket-index loads (2 vector
// loads replace 8 scalar; same i0..i7, same sum order -> bit-identical).
// mega_prep scatter: 4 edges/thread via int4 dst/src loads -> 4 independent
// atomicAdd chains in flight (was 1) to cut the ~35us latency pole.
// gemm / pool / prep_w / bounds / prep_x unchanged from R19.

#define FH 128
#define OUTD 256
#define SLOTS 64
#define PWB 96   // weight-prep blocks: 48 pairs x 8 ot = 384 waves

typedef unsigned int u32;
typedef unsigned short u16;
typedef __attribute__((ext_vector_type(8))) _Float16 f16frag;
typedef __attribute__((ext_vector_type(4))) float f4frag;

typedef __attribute__((address_space(3))) u32 lds_u32;
typedef __attribute__((address_space(1))) const u32 glb_u32;

__device__ inline void async_copy16(const void* g, void* l) {
    __builtin_amdgcn_global_load_lds((glb_u32*)g, (lds_u32*)l, 16, 0, 0);
}

// ====== mega prep: prep_w | scatter | graph bounds | prep_x (in block order)
// [0,PWB): weights->B frags (latency-bound, launched FIRST)
// [PWB, PWB+SC): bucket scatter, 4 edges/thread (atomic cursor)
// [+GBND): per-graph node ranges
// rest: x->fp16 (BW-bound filler)
__global__ void mega_prep(const float* __restrict__ x, u16* __restrict__ x16, int n4,
                          const float* __restrict__ W0, const float* __restrict__ W1,
                          const float* __restrict__ W2, const float* __restrict__ W3,
                          const float* __restrict__ W4, const float* __restrict__ W5,
                          uint4* __restrict__ Bf,
                          const int* __restrict__ src, const int* __restrict__ dst,
                          int* __restrict__ cursor, int* __restrict__ esrc, int E, int SC,
                          const int* __restrict__ batch, int* __restrict__ gstart,
                          int n, int g, int GBND) {
    int blk = blockIdx.x;
    if (blk < PWB) {
        // one wave per (pair, ot): pair = wid>>3, ot = wid&7
        int wid = blk * 4 + (threadIdx.x >> 6);      // 0..383
        int pair = wid >> 3;                         // 0..47
        int ot = wid & 7;
        int ks = pair & 7;
        int arr = pair >> 3;
        int l = threadIdx.x & 63;
        const float* Ws[6] = {W0, W1, W2, W3, W4, W5};
        const float* W = Ws[arr];
        bool use_lo = (ks >= 4);
        int kb = (ks & 3) * 32 + (l >> 4) * 8;
        int o = ot * 16 + (l & 15);
        float4 v0 = *(const float4*)(W + o * 128 + kb);
        float4 v1 = *(const float4*)(W + o * 128 + kb + 4);
        float vv[8] = {v0.x, v0.y, v0.z, v0.w, v1.x, v1.y, v1.z, v1.w};
        u32 h[8];
        #pragma unroll
        for (int i = 0; i < 8; ++i) {
            float v = vv[i];
            __half hi = __float2half(v);
            if (use_lo) {
                float rem = v - __half2float(hi);
                __half lo = __float2half(rem);
                h[i] = *(u16*)&lo;
            } else {
                h[i] = *(u16*)&hi;
            }
        }
        uint4 u;
        u.x = h[0] | (h[1] << 16);
        u.y = h[2] | (h[3] << 16);
        u.z = h[4] | (h[5] << 16);
        u.w = h[6] | (h[7] << 16);
        Bf[(size_t)arr * 4096 + (ks * 8 + ot) * 64 + l] = u;
    } else if (blk < PWB + SC) {
        int e = (blk - PWB) * 1024 + threadIdx.x * 4;
        if (e + 3 < E) {
            int4 dv = *(const int4*)(dst + e);
            int4 sv = *(const int4*)(src + e);
            int p0 = atomicAdd(&cursor[dv.x], 1);
            int p1 = atomicAdd(&cursor[dv.y], 1);
            int p2 = atomicAdd(&cursor[dv.z], 1);
            int p3 = atomicAdd(&cursor[dv.w], 1);
            if (p0 < SLOTS) esrc[(size_t)dv.x * SLOTS + p0] = sv.x;
            if (p1 < SLOTS) esrc[(size_t)dv.y * SLOTS + p1] = sv.y;
            if (p2 < SLOTS) esrc[(size_t)dv.z * SLOTS + p2] = sv.z;
            if (p3 < SLOTS) esrc[(size_t)dv.w * SLOTS + p3] = sv.w;
        } else {
            for (int k = 0; k < 4; ++k) {
                int ee = e + k;
                if (ee < E) {
                    int d = dst[ee];
                    int pos = atomicAdd(&cursor[d], 1);
                    if (pos < SLOTS) esrc[(size_t)d * SLOTS + pos] = src[ee];
                }
            }
        }
    } else if (blk < PWB + SC + GBND) {
        int i = (blk - PWB - SC) * 256 + threadIdx.x;
        if (i >= n) return;
        int b = batch[i];
        int pb = (i == 0) ? -1 : batch[i - 1];
        for (int q = pb + 1; q <= b; ++q) gstart[q] = i;
        if (i == n - 1) {
            for (int q = b + 1; q <= g; ++q) gstart[q] = n;
        }
    } else {
        int id = (blk - PWB - SC - GBND) * 256 + threadIdx.x;
        if (id >= n4) return;
        float4 v = *(const float4*)(x + (size_t)id * 4);
        __half h0 = __float2half(v.x), h1 = __float2half(v.y);
        __half h2 = __float2half(v.z), h3 = __float2half(v.w);
        ushort4 s;
        s.x = *(u16*)&h0; s.y = *(u16*)&h1; s.z = *(u16*)&h2; s.w = *(u16*)&h3;
        *(ushort4*)(x16 + (size_t)id * 4) = s;
    }
}

// --------------------------------------------------- mean aggregation
// 16 lanes per node; lane covers 8 fp16 features (uint4 = 16B); x8 edge
// unroll with int4 bucket-index loads (contiguous, 32B-aligned). Edge list
// = fixed-stride bucket [node*SLOTS, node*SLOTS+deg). Summation order
// identical to R19 -> bit-identical output.
__device__ inline void add8(float* a, uint4 u) {
    float2 f0 = __half22float2(*(__half2*)&u.x);
    float2 f1 = __half22float2(*(__half2*)&u.y);
    float2 f2 = __half22float2(*(__half2*)&u.z);
    float2 f3 = __half22float2(*(__half2*)&u.w);
    a[0] += f0.x; a[1] += f0.y; a[2] += f1.x; a[3] += f1.y;
    a[4] += f2.x; a[5] += f2.y; a[6] += f3.x; a[7] += f3.y;
}

__global__ void agg_kernel(const u16* __restrict__ h16,
                           const int* __restrict__ deg, const int* __restrict__ esrc,
                           u16* __restrict__ agg16, int n_nodes) {
    int node = blockIdx.x * 16 + (threadIdx.x >> 4);
    if (node >= n_nodes) return;
    int lane = threadIdx.x & 15;
    int f = lane * 8;
    int d = deg[node];
    int s0 = node * SLOTS, s1 = s0 + min(d, SLOTS);
    float a0[8] = {0, 0, 0, 0, 0, 0, 0, 0};
    float a1[8] = {0, 0, 0, 0, 0, 0, 0, 0};
    float a2[8] = {0, 0, 0, 0, 0, 0, 0, 0};
    float a3[8] = {0, 0, 0, 0, 0, 0, 0, 0};
    int j = s0;
    for (; j + 8 <= s1; j += 8) {
        int4 e0 = *(const int4*)(esrc + j);
        int4 e1 = *(const int4*)(esrc + j + 4);
        uint4 u0 = *(const uint4*)(h16 + (size_t)e0.x * FH + f);
        uint4 u1 = *(const uint4*)(h16 + (size_t)e0.y * FH + f);
        uint4 u2 = *(const uint4*)(h16 + (size_t)e0.z * FH + f);
        uint4 u3 = *(const uint4*)(h16 + (size_t)e0.w * FH + f);
        uint4 u4 = *(const uint4*)(h16 + (size_t)e1.x * FH + f);
        uint4 u5 = *(const uint4*)(h16 + (size_t)e1.y * FH + f);
        uint4 u6 = *(const uint4*)(h16 + (size_t)e1.z * FH + f);
        uint4 u7 = *(const uint4*)(h16 + (size_t)e1.w * FH + f);
        add8(a0, u0); add8(a1, u1); add8(a2, u2); add8(a3, u3);
        add8(a0, u4); add8(a1, u5); add8(a2, u6); add8(a3, u7);
    }
    if (j + 4 <= s1) {
        int4 e0 = *(const int4*)(esrc + j);
        uint4 u0 = *(const uint4*)(h16 + (size_t)e0.x * FH + f);
        uint4 u1 = *(const uint4*)(h16 + (size_t)e0.y * FH + f);
        uint4 u2 = *(const uint4*)(h16 + (size_t)e0.z * FH + f);
        uint4 u3 = *(const uint4*)(h16 + (size_t)e0.w * FH + f);
        add8(a0, u0); add8(a1, u1); add8(a2, u2); add8(a3, u3);
        j += 4;
    }
    for (; j < s1; ++j) {
        uint4 u0 = *(const uint4*)(h16 + (size_t)esrc[j] * FH + f);
        add8(a0, u0);
    }
    float di = 1.0f / (float)max(d, 1);
    u32 oh[8];
    #pragma unroll
    for (int i = 0; i < 8; ++i) {
        __half hv = __float2half((a0[i] + a1[i] + a2[i] + a3[i]) * di);
        oh[i] = *(u16*)&hv;
    }
    uint4 w;
    w.x = oh[0] | (oh[1] << 16);
    w.y = oh[2] | (oh[3] << 16);
    w.z = oh[4] | (oh[5] << 16);
    w.w = oh[6] | (oh[7] << 16);
    *(uint4*)(agg16 + (size_t)node * FH + f) = w;
}

// ----------------------------------------------------------- MFMA SAGE GEMM
// Exact R11/R15 structure (proven best): 256 thr / 4 waves, 192-node tile,
// per-source async global_load_lds B staging (64 KB), A prefetch in regs,
// pure-LDS K-loop (hi then lo phase).
__global__ __launch_bounds__(256, 2)
void mfma_gemm(const u16* __restrict__ A1, const u16* __restrict__ A2,
               const uint4* __restrict__ Bf1, const uint4* __restrict__ Bf2,
               const float* __restrict__ bias, u16* __restrict__ out16,
               int do_relu) {
    __shared__ uint4 Bl[4096];  // 64 KB
    int tid = threadIdx.x;
    int l = tid & 63;
    int wv = tid >> 6;
    int bn0 = blockIdx.x * 192 + wv * 48;
    int m = l & 15, q = l >> 4;

    f4frag acc[3][8];
    #pragma unroll
    for (int i = 0; i < 3; ++i)
        #pragma unroll
        for (int o = 0; o < 8; ++o)
            acc[i][o] = (f4frag){0.f, 0.f, 0.f, 0.f};

    #pragma unroll
    for (int p = 0; p < 2; ++p) {
        const u16* P = p ? A2 : A1;
        const uint4* Bf = p ? Bf2 : Bf1;

        // A prefetch (registers; in flight across the barrier)
        f16frag Af[3][4];
        #pragma unroll
        for (int nt = 0; nt < 3; ++nt)
            #pragma unroll
            for (int s = 0; s < 4; ++s)
                Af[nt][s] = *(const f16frag*)(P + (size_t)(bn0 + nt * 16 + m) * FH + s * 32 + q * 8);

        __syncthreads();   // all waves done with previous source's Bl

        #pragma unroll
        for (int u = 0; u < 16; ++u)
            async_copy16(Bf + (size_t)u * 256 + wv * 64 + l,
                         &Bl[u * 256 + wv * 64]);
        __syncthreads();   // drains vmcnt -> staging complete

        #pragma unroll
        for (int s = 0; s < 4; ++s) {
            {
                f16frag B[8];
                #pragma unroll
                for (int ot = 0; ot < 8; ++ot)
                    B[ot] = *(const f16frag*)&Bl[(size_t)(s * 8 + ot) * 64 + l];
                #pragma unroll
                for (int ot = 0; ot < 8; ++ot)
                    #pragma unroll
                    for (int nt = 0; nt < 3; ++nt)
                        acc[nt][ot] = __builtin_amdgcn_mfma_f32_16x16x32_f16(Af[nt][s], B[ot], acc[nt][ot], 0, 0, 0);
            }
            {
                f16frag B[8];
                #pragma unroll
                for (int ot = 0; ot < 8; ++ot)
                    B[ot] = *(const f16frag*)&Bl[(size_t)((s + 4) * 8 + ot) * 64 + l];
                #pragma unroll
                for (int ot = 0; ot < 8; ++ot)
                    #pragma unroll
                    for (int nt = 0; nt < 3; ++nt)
                        acc[nt][ot] = __builtin_amdgcn_mfma_f32_16x16x32_f16(Af[nt][s], B[ot], acc[nt][ot], 0, 0, 0);
            }
        }
    }

    #pragma unroll
    for (int nt = 0; nt < 3; ++nt)
        #pragma unroll
        for (int r = 0; r < 4; ++r) {
            int node = bn0 + nt * 16 + q * 4 + r;
            #pragma unroll
            for (int ot = 0; ot < 8; ++ot) {
                float v = acc[nt][ot][r] + bias[ot * 16 + m];
                if (do_relu) v = fmaxf(v, 0.f);
                __half hv = __float2half(v);
                out16[(size_t)node * FH + ot * 16 + m] = *(u16*)&hv;
            }
        }
}

// --------------------------------------------- fused pooling + final linear
__global__ __launch_bounds__(256, 2)
void pool_final(const u16* __restrict__ h16, const int* __restrict__ gstart,
                const float* __restrict__ Wlin, const float* __restrict__ blin,
                float* __restrict__ out) {
    __shared__ float smax[16][FH];
    __shared__ float ssum[16][FH];
    __shared__ float pr[2 * FH];
    int g = blockIdx.x;
    int tid = threadIdx.x;
    int way = tid >> 4;
    int lane = tid & 15;
    int f = lane * 8;
    int s = gstart[g], e = gstart[g + 1];

    float mx[8], sm[8];
    #pragma unroll
    for (int i = 0; i < 8; ++i) { mx[i] = -INFINITY; sm[i] = 0.f; }
    for (int n = s + way; n < e; n += 16) {
        uint4 u = *(const uint4*)(h16 + (size_t)n * FH + f);
        float2 f0 = __half22float2(*(__half2*)&u.x);
        float2 f1 = __half22float2(*(__half2*)&u.y);
        float2 f2 = __half22float2(*(__half2*)&u.z);
        float2 f3 = __half22float2(*(__half2*)&u.w);
        float v[8] = {f0.x, f0.y, f1.x, f1.y, f2.x, f2.y, f3.x, f3.y};
        #pragma unroll
        for (int i = 0; i < 8; ++i) {
            mx[i] = fmaxf(mx[i], v[i]);
            sm[i] += v[i];
        }
    }
    #pragma unroll
    for (int i = 0; i < 8; ++i) {
        smax[way][f + i] = mx[i];
        ssum[way][f + i] = sm[i];
    }
    __syncthreads();
    int c = e - s;
    if (tid < FH) {
        float m2 = -INFINITY, s2 = 0.f;
        #pragma unroll
        for (int w2 = 0; w2 < 16; ++w2) {
            m2 = fmaxf(m2, smax[w2][tid]);
            s2 += ssum[w2][tid];
        }
        pr[tid] = (c > 0) ? m2 : 0.f;
        pr[FH + tid] = s2 / (float)max(c, 1);
    }
    __syncthreads();
    int o = tid;
    const float4* wr = (const float4*)(Wlin + (size_t)o * (2 * FH));
    float acc = 0.f;
    #pragma unroll
    for (int j = 0; j < (2 * FH) / 4; ++j) {
        float4 wv = wr[j];
        acc += wv.x * pr[j * 4 + 0] + wv.y * pr[j * 4 + 1] +
               wv.z * pr[j * 4 + 2] + wv.w * pr[j * 4 + 3];
    }
    out[(size_t)g * OUTD + o] = acc + blin[o];
}

extern "C" void kernel_launch(void* const* d_in, const int* in_sizes, int n_in,
                              void* d_out, int out_size, void* d_ws, size_t ws_size,
                              hipStream_t stream) {
    const float* x     = (const float*)d_in[0];
    const int*   ei    = (const int*)d_in[1];
    const int*   batch = (const int*)d_in[2];
    const float* W1l = (const float*)d_in[3];
    const float* b1  = (const float*)d_in[4];
    const float* W1r = (const float*)d_in[5];
    const float* W2l = (const float*)d_in[6];
    const float* b2  = (const float*)d_in[7];
    const float* W2r = (const float*)d_in[8];
    const float* W3l = (const float*)d_in[9];
    const float* b3  = (const float*)d_in[10];
    const float* W3r = (const float*)d_in[11];
    const float* Wlin = (const float*)d_in[12];
    const float* blin = (const float*)d_in[13];
    float* out = (float*)d_out;

    const int E = in_sizes[1] / 2;
    const int N = in_sizes[2];
    const int G = out_size / OUTD;
    const int* src = ei;
    const int* dst = ei + E;
    const int GB = (N + 191) / 192;
    const int NP = GB * 192;

    // ---- workspace carve-up ----
    char* w = (char*)d_ws;
    auto alloc = [&](size_t bytes) {
        void* p = (void*)w;
        w += (bytes + 255) & ~(size_t)255;
        return p;
    };
    int*   cursor = (int*)alloc((size_t)N * sizeof(int));          // deg after scatter
    int*   esrc   = (int*)alloc((size_t)N * SLOTS * sizeof(int));  // bucketed edge list
    int*   gstart = (int*)alloc((size_t)(G + 1) * sizeof(int));
    u16*   x16    = (u16*)alloc((size_t)NP * FH * sizeof(u16));
    u16*   agg16  = (u16*)alloc((size_t)NP * FH * sizeof(u16));
    u16*   hA16   = (u16*)alloc((size_t)NP * FH * sizeof(u16));
    u16*   hB16   = (u16*)alloc((size_t)NP * FH * sizeof(u16));
    uint4* BF     = (uint4*)alloc((size_t)6 * 4096 * sizeof(uint4));
    (void)ws_size;

    // ---- single prep dispatch: prep_w | scatter | bounds | prep_x ----
    hipMemsetAsync(cursor, 0, (size_t)N * sizeof(int), stream);
    const int n4 = N * 32;
    const int PX = (n4 + 255) / 256;
    const int SC = (E + 1023) / 1024;   // 4 edges/thread
    const int GBND = (N + 255) / 256;
    mega_prep<<<PWB + SC + GBND + PX, 256, 0, stream>>>(
        x, x16, n4,
        W1l, W1r, W2l, W2r, W3l, W3r, BF,
        src, dst, cursor, esrc, E, SC,
        batch, gstart, N, G, GBND);

    const int agg_grid = (N + 15) / 16;

    // ---- layer 1 ----
    agg_kernel<<<agg_grid, 256, 0, stream>>>(x16, cursor, esrc, agg16, N);
    mfma_gemm<<<GB, 256, 0, stream>>>(agg16, x16, BF + 0 * 4096, BF + 1 * 4096, b1, hA16, 1);
    // ---- layer 2 ----
    agg_kernel<<<agg_grid, 256, 0, stream>>>(hA16, cursor, esrc, agg16, N);
    mfma_gemm<<<GB, 256, 0, stream>>>(agg16, hA16, BF + 2 * 4096, BF + 3 * 4096, b2, hB16, 1);
    // ---- layer 3 ----
    agg_kernel<<<agg_grid, 256, 0, stream>>>(hB16, cursor, esrc, agg16, N);
    mfma_gemm<<<GB, 256, 0, stream>>>(agg16, hB16, BF + 4 * 4096, BF + 5 * 4096, b3, hA16, 0);

    // ---- fused pool + head ----
    pool_final<<<G, 256, 0, stream>>>(hA16, gstart, Wlin, blin, out);
}